// Round 14
// baseline (729.469 us; speedup 1.0000x reference)
//
#include <hip/hip_runtime.h>

// Sinkhorn EMD, B=8, N=2048, eps=0.005, 50 iters.
// R14: straggler-free sparse passes. Each sparse pass = 320 fixed chunk
// slots (64 rows x 5 chunks of 64 cols, CAP=320); wave w takes slots
// {w,w+16,...} (20 each) -> per-wave work uniform regardless of per-row
// candidate counts. Per-row partials via LDS atomicAdd (ds_add_f32);
// 64 threads finalize L/pot and re-zero partials (no extra sync).
// Row state (Lp, cnt) in LDS so any thread can finalize any row.
// dis uses the same balanced slot loop. Dense/online/build per-wave
// (already uniform). R13's distributed-arrival barrier kept.
// Invariants: IC-coherent atomics no fences (R6), no scratch spill (R8),
// online 0-5, builds {6,7}+24k, MARGIN=48 (R9-R13, absmax 0.0).

#define BB 8
#define NN 2048
#define NPASS 100
#define ONLINE_PASSES 6
#define RPW 4
#define GRID_BLOCKS 256
#define BLOCKS_PER_BATCH 32
#define TPB 1024
#define CAP 320
#define CPR 5                  // chunks (of 64) per row
#define SLOTS_PER_WAVE 20      // 320 slots / 16 waves
#define MARGIN 48.0f

constexpr float EPSV = 0.005f;
constexpr float KS   = EPSV * 0.69314718055994531f; // eps*ln2
constexpr float INVK = 1.0f / KS;
constexpr float C1V  = -EPSV * 7.6246189861593985f; // eps*log(1/2048)
constexpr float C1K  = C1V * INVK;
constexpr float KQ4  = KS * 0.25f;
constexpr float TWOI = 2.0f * INVK;
constexpr float HK   = KS * 0.5f;

__device__ __forceinline__ float fexp2(float x) { return __builtin_amdgcn_exp2f(x); }
__device__ __forceinline__ float flog2(float x) { return __builtin_amdgcn_logf(x); }

__device__ __forceinline__ float cohLoad(const float* p) {
    return __hip_atomic_load(p, __ATOMIC_RELAXED, __HIP_MEMORY_SCOPE_AGENT);
}
__device__ __forceinline__ void cohStore(float* p, float v) {
    __hip_atomic_store(p, v, __ATOMIC_RELAXED, __HIP_MEMORY_SCOPE_AGENT);
}
__device__ __forceinline__ int cohLoadI(const int* p) {
    return __hip_atomic_load(p, __ATOMIC_RELAXED, __HIP_MEMORY_SCOPE_AGENT);
}
__device__ __forceinline__ void cohStoreI(int* p, int v) {
    __hip_atomic_store(p, v, __ATOMIC_RELAXED, __HIP_MEMORY_SCOPE_AGENT);
}

// distributed-arrival barrier (R13): own-slot store + parallel poll
__device__ __forceinline__ void barrier_sync(int* arr, int rb, int target) {
    __syncthreads();
    if (threadIdx.x < 64) {
        if (threadIdx.x == 0) cohStoreI(&arr[rb], target);
        const int slot = threadIdx.x & 31;
        while (true) {
            int v = cohLoadI(&arr[slot]);
            if (__ballot(v >= target) == ~0ull) break;
            __builtin_amdgcn_s_sleep(1);
        }
    }
    __syncthreads();
}

__device__ __forceinline__ void barrier_ctr(int* ctr, int target) {
    __syncthreads();
    if (threadIdx.x == 0) {
        __hip_atomic_fetch_add(ctr, 1, __ATOMIC_RELAXED, __HIP_MEMORY_SCOPE_AGENT);
        while (__hip_atomic_load(ctr, __ATOMIC_RELAXED, __HIP_MEMORY_SCOPE_AGENT) < target) {
            __builtin_amdgcn_s_sleep(1);
        }
    }
    __syncthreads();
}

__global__ void __launch_bounds__(TPB, 4) emd_persist(
    const float* __restrict__ preds, const float* __restrict__ gts,
    float* __restrict__ fpot, float* __restrict__ gpot,
    float* __restrict__ partials, int* __restrict__ barArr, int* __restrict__ gctr,
    float* __restrict__ out)
{
    __shared__ float4 sjall[2 * NN];              // 64KB: side0=gts, side1=preds
    __shared__ float  sa[NN];                     // 8KB staged pots (dense passes)
    __shared__ float  sLp[2][64];                 // prev log-sum per row/side
    __shared__ int    scn[2][64];                 // candidate counts
    __shared__ float  spart[64];                  // per-row partial sums
    __shared__ float  wred[16];
    __shared__ unsigned short slist[2][64][CAP];  // 80KB

    const int blk  = blockIdx.x;
    const int b    = blk & 7;
    const int rb   = blk >> 3;
    const int wave = threadIdx.x >> 6;
    const int lane = threadIdx.x & 63;
    const int rowL0 = wave * RPW;
    const int row0  = rb * 64 + rowL0;

    const float* pb  = preds + (size_t)b * NN * 3;
    const float* gbp = gts   + (size_t)b * NN * 3;
    float* fb = fpot + (size_t)b * NN;
    float* gb = gpot + (size_t)b * NN;
    int*   bar = barArr + b * 64;

    for (int t = threadIdx.x; t < NN; t += TPB) {
        float gx = gbp[3*t], gy = gbp[3*t+1], gz = gbp[3*t+2];
        float Gx = gx*TWOI, Gy = gy*TWOI, Gz = gz*TWOI;
        sjall[t] = make_float4(Gx, Gy, Gz, -KQ4*(Gx*Gx+Gy*Gy+Gz*Gz));
        float qx = pb[3*t], qy = pb[3*t+1], qz = pb[3*t+2];
        float Qx = qx*TWOI, Qy = qy*TWOI, Qz = qz*TWOI;
        sjall[NN+t] = make_float4(Qx, Qy, Qz, -KQ4*(Qx*Qx+Qy*Qy+Qz*Qz));
    }
    if (threadIdx.x < 64) spart[threadIdx.x] = 0.f;
    __syncthreads();

    // dense-path register row constants (both sides)
    float qxf[RPW], qyf[RPW], qzf[RPW], pcf[RPW];
    float qxg[RPW], qyg[RPW], qzg[RPW], pcg[RPW];
#pragma unroll
    for (int r = 0; r < RPW; ++r) {
        float4 df = sjall[NN + row0 + r];
        qxf[r] = HK*df.x; qyf[r] = HK*df.y; qzf[r] = HK*df.z;
        pcf[r] = C1V - KS*df.w;
        float4 dg = sjall[row0 + r];
        qxg[r] = HK*dg.x; qyg[r] = HK*dg.y; qzg[r] = HK*dg.z;
        pcg[r] = C1V - KS*dg.w;
    }

#pragma unroll 1
    for (int pass = 0; pass < NPASS; ++pass) {
        const int odd = pass & 1;
        const int colOff = odd ? NN : 0;
        const int rso    = odd ? 0  : NN;
        const float* pin  = odd ? fb : gb;
        float*       pout = odd ? gb : fb;
        const bool isBuild  = (pass >= ONLINE_PASSES) &&
                              (((pass - ONLINE_PASSES) % 24) < 2);
        const bool isSparse = (pass >= ONLINE_PASSES) && !isBuild;

        if (isSparse) {
            // ---- balanced slot loop: uniform work per wave ----
#pragma unroll 4
            for (int k = 0; k < SLOTS_PER_WAVE; ++k) {
                const int s = wave + (k << 4);     // 0..319
                const int r = s / CPR;
                const int c = s - r * CPR;
                const int cnt = scn[odd][r];
                if (cnt <= CAP && c*64 < cnt) {
                    const float Mr = sLp[odd][r];
                    const int kk = c*64 + lane;
                    const int j  = slist[odd][r][kk < cnt ? kk : 0];
                    float4 d  = sjall[colOff + j];
                    float  p  = cohLoad(&pin[j]);
                    float4 dr = sjall[rso + rb*64 + r];   // broadcast read
                    float x = fmaf(HK*dr.x, d.x, fmaf(HK*dr.y, d.y,
                              fmaf(HK*dr.z, d.z, fmaf(p, INVK, d.w))));
                    float e = (kk < cnt) ? fexp2(fminf(x - Mr, 100.f)) : 0.f;
                    for (int off = 1; off < 64; off <<= 1) e += __shfl_xor(e, off, 64);
                    if (lane == 0) atomicAdd(&spart[r], e);
                }
            }
            // rare overflow fallback: home wave dense-sweeps its row
#pragma unroll
            for (int r0 = 0; r0 < RPW; ++r0) {
                const int r = rowL0 + r0;
                const int cnt = scn[odd][r];
                if (cnt > CAP) {
                    const float Mr = sLp[odd][r];
                    const float qx = odd ? qxg[r0] : qxf[r0];
                    const float qy = odd ? qyg[r0] : qyf[r0];
                    const float qz = odd ? qzg[r0] : qzf[r0];
                    float s1 = 0.f;
#pragma unroll 1
                    for (int c = 0; c < 32; ++c) {
                        int j = c*64 + lane;
                        float4 d = sjall[colOff + j];
                        float aw = fmaf(cohLoad(&pin[j]), INVK, d.w);
                        float x  = fmaf(qx, d.x, fmaf(qy, d.y, fmaf(qz, d.z, aw)));
                        s1 += fexp2(fminf(x - Mr, 100.f));
                    }
                    for (int off = 1; off < 64; off <<= 1) s1 += __shfl_xor(s1, off, 64);
                    if (lane == 0) atomicAdd(&spart[r], s1);
                }
            }
            __syncthreads();
            if (threadIdx.x < 64) {
                const int r = threadIdx.x;
                float Mr = sLp[odd][r];
                float sv = spart[r];
                float L  = Mr + flog2(fmaxf(sv, 1e-37f));
                sLp[odd][r] = L;
                spart[r] = 0.f;                    // re-zero for next pass
                float4 dr = sjall[rso + rb*64 + r];
                cohStore(&pout[rb*64 + r], (C1V - KS*dr.w) - KS * L);
            }
        } else {
            // ---- dense-type: stage sa, per-wave full sweep ----
            float qx[RPW], qy[RPW], qz[RPW], pc[RPW], M[RPW];
#pragma unroll
            for (int r = 0; r < RPW; ++r) {
                qx[r] = odd ? qxg[r] : qxf[r];
                qy[r] = odd ? qyg[r] : qyf[r];
                qz[r] = odd ? qzg[r] : qzf[r];
                pc[r] = odd ? pcg[r] : pcf[r];
                M[r]  = sLp[odd][rowL0 + r];      // valid for pass>=6
            }
            for (int t = threadIdx.x; t < NN; t += TPB)
                sa[t] = cohLoad(&pin[t]) * INVK;
            __syncthreads();

            if (pass < ONLINE_PASSES) {
                float m[RPW], s[RPW];
#pragma unroll
                for (int r = 0; r < RPW; ++r) { m[r] = -1e30f; s[r] = 0.f; }
#pragma unroll 2
                for (int c = 0; c < 32; ++c) {
                    float4 d = sjall[colOff + c*64 + lane];
                    float aw = d.w + sa[c*64 + lane];
#pragma unroll
                    for (int r = 0; r < RPW; ++r) {
                        float x  = fmaf(qx[r], d.x, fmaf(qy[r], d.y, fmaf(qz[r], d.z, aw)));
                        float mn = fmaxf(m[r], x);
                        s[r] = fmaf(s[r], fexp2(m[r]-mn), fexp2(x-mn));
                        m[r] = mn;
                    }
                }
#pragma unroll
                for (int r = 0; r < RPW; ++r) {
                    float mm = m[r], sv = s[r];
                    for (int off = 1; off < 64; off <<= 1) {
                        float mo = __shfl_xor(mm, off, 64);
                        float so = __shfl_xor(sv, off, 64);
                        float mn = fmaxf(mm, mo);
                        sv = fmaf(sv, fexp2(mm-mn), so * fexp2(mo-mn));
                        mm = mn;
                    }
                    float L = mm + flog2(fmaxf(sv, 1e-37f));
                    if (lane == 0) {
                        sLp[odd][rowL0 + r] = L;
                        cohStore(&pout[row0 + r], pc[r] - KS * L);
                    }
                }
            } else {
                // build: dense fixed-shift + compaction
                float s[RPW]; int cn[RPW];
#pragma unroll
                for (int r = 0; r < RPW; ++r) { s[r] = 0.f; cn[r] = 0; }
#pragma unroll 1
                for (int c = 0; c < 32; ++c) {
                    int j = c*64 + lane;
                    float4 d = sjall[colOff + j];
                    float aw = d.w + sa[j];
#pragma unroll
                    for (int r = 0; r < RPW; ++r) {
                        float x = fmaf(qx[r], d.x, fmaf(qy[r], d.y, fmaf(qz[r], d.z, aw)));
                        s[r] += fexp2(fminf(x - M[r], 100.f));
                        bool pred = (x >= M[r] - MARGIN);
                        unsigned long long mask = __ballot((int)pred);
                        if (pred) {
                            int pos = cn[r] + __popcll(mask & ((1ull << lane) - 1ull));
                            if (pos < CAP) slist[odd][rowL0 + r][pos] = (unsigned short)j;
                        }
                        cn[r] += __popcll(mask);
                    }
                }
#pragma unroll
                for (int r = 0; r < RPW; ++r) {
                    float sv = s[r];
                    for (int off = 1; off < 64; off <<= 1) sv += __shfl_xor(sv, off, 64);
                    float L = M[r] + flog2(fmaxf(sv, 1e-37f));
                    if (lane == 0) {
                        sLp[odd][rowL0 + r] = L;
                        scn[odd][rowL0 + r] = cn[r];
                        cohStore(&pout[row0 + r], pc[r] - KS * L);
                    }
                }
            }
        }
        barrier_sync(bar, rb, pass + 1);
    }

    // ---- dis: balanced slot loop over f-lists (side 0) ----
    {
        float accL = 0.f;
#pragma unroll 4
        for (int k = 0; k < SLOTS_PER_WAVE; ++k) {
            const int s = wave + (k << 4);
            const int r = s / CPR;
            const int c = s - r * CPR;
            const int cnt = scn[0][r];
            if (cnt <= CAP && c*64 < cnt) {
                float4 dr = sjall[NN + rb*64 + r];
                float px = HK*dr.x, py = HK*dr.y, pz = HK*dr.z;
                float pn = -KS*dr.w;
                float bb2 = C1K - sLp[0][r];
                const int kk = c*64 + lane;
                const int j  = slist[0][r][kk < cnt ? kk : 0];
                float4 d = sjall[j];
                float aw = fmaf(cohLoad(&gb[j]), INVK, d.w);
                float dot = fmaf(px, d.x, fmaf(py, d.y, pz*d.z));
                float y   = dot + aw + bb2;
                float e   = (kk < cnt) ? fexp2(fminf(y, 80.f)) : 0.f;
                accL = fmaf(e, fmaf(-KS, dot, pn - KS*d.w), accL);
            }
        }
#pragma unroll
        for (int r0 = 0; r0 < RPW; ++r0) {
            const int r = rowL0 + r0;
            const int cnt = scn[0][r];
            if (cnt > CAP) {
                float bb2 = C1K - sLp[0][r];
                float pn  = pcf[r0] - C1V;
#pragma unroll 1
                for (int c = 0; c < 32; ++c) {
                    int j = c*64 + lane;
                    float4 d = sjall[j];
                    float aw = fmaf(cohLoad(&gb[j]), INVK, d.w);
                    float dot = fmaf(qxf[r0], d.x, fmaf(qyf[r0], d.y, qzf[r0]*d.z));
                    float y   = dot + aw + bb2;
                    float e   = fexp2(fminf(y, 80.f));
                    accL = fmaf(e, fmaf(-KS, dot, pn - KS*d.w), accL);
                }
            }
        }
        for (int off = 1; off < 64; off <<= 1) accL += __shfl_xor(accL, off, 64);
        if (lane == 0) wred[wave] = accL;
        __syncthreads();
        if (threadIdx.x == 0) {
            float v = 0.f;
            for (int w = 0; w < 16; ++w) v += wred[w];
            cohStore(&partials[blk], v);
        }
    }

    barrier_ctr(gctr, GRID_BLOCKS);

    if (blk == 0) {
        float v = (threadIdx.x < GRID_BLOCKS) ? cohLoad(&partials[threadIdx.x]) : 0.f;
        for (int off = 1; off < 64; off <<= 1) v += __shfl_xor(v, off, 64);
        if (lane == 0) wred[wave] = v;
        __syncthreads();
        if (threadIdx.x == 0) {
            float t2 = 0.f;
            for (int w = 0; w < 16; ++w) t2 += wred[w];
            out[0] = t2 * (1.0f / BB);
        }
    }
}

extern "C" void kernel_launch(void* const* d_in, const int* in_sizes, int n_in,
                              void* d_out, int out_size, void* d_ws, size_t ws_size,
                              hipStream_t stream) {
    const float* preds = (const float*)d_in[0];
    const float* gts   = (const float*)d_in[1];
    float* fp       = (float*)d_ws;
    float* gp       = fp + BB * NN;
    float* partials = gp + BB * NN;
    int*   barArr   = (int*)(partials + GRID_BLOCKS);  // 8 x 64
    int*   gctr     = barArr + BB * 64;                // [32]
    float* out      = (float*)d_out;

    size_t zbytes = (size_t)(2 * BB * NN + GRID_BLOCKS) * sizeof(float)
                  + (size_t)(BB * 64 + 32) * sizeof(int);
    hipMemsetAsync(d_ws, 0, zbytes, stream);

    emd_persist<<<dim3(GRID_BLOCKS), dim3(TPB), 0, stream>>>(
        preds, gts, fp, gp, partials, barArr, gctr, out);
}